// Round 1
// baseline (707.987 us; speedup 1.0000x reference)
//
#include <hip/hip_runtime.h>
#include <cstdint>
#include <cstddef>

// Problem constants
#define Bb   256
#define Tt   512
#define Ii   300
#define Hh   128
#define G4   512      // 4*H
#define KP   320      // K padded to multiple of 32 for MFMA
#define Mm   (Bb*Tt)  // 131072 rows of phase-1 GEMM

typedef _Float16 h2v   __attribute__((ext_vector_type(2)));
typedef _Float16 half8 __attribute__((ext_vector_type(8)));
typedef float    f32x4 __attribute__((ext_vector_type(4)));

static __device__ __forceinline__ h2v as_h2(unsigned int u){ union{unsigned int u; h2v h;} c; c.u=u; return c.h; }
static __device__ __forceinline__ unsigned int as_u32(h2v h){ union{unsigned int u; h2v h;} c; c.h=h; return c.u; }

#if __has_builtin(__builtin_amdgcn_fdot2)
#define FDOT2(a,b,c) __builtin_amdgcn_fdot2((a),(b),(c),false)
#else
static __device__ __forceinline__ float FDOT2(h2v a, h2v b, float c){
  return c + (float)a[0]*(float)b[0] + (float)a[1]*(float)b[1];
}
#endif

// ---------------- conversion: x fp32 [131072,300] -> f16 padded [131072,320] ----------------
__global__ __launch_bounds__(256) void conv_x(const float* __restrict__ x, unsigned int* __restrict__ x16){
  int idx = blockIdx.x*256 + threadIdx.x;      // half2 index; total 131072*160, grid exact
  int r   = idx / 160;
  int kk2 = idx - r*160;
  int kk  = kk2*2;
  const float* xr = x + (size_t)r*Ii;
  float v0 = (kk   < Ii) ? xr[kk]   : 0.f;
  float v1 = (kk+1 < Ii) ? xr[kk+1] : 0.f;
  h2v h; h[0] = (_Float16)v0; h[1] = (_Float16)v1;
  x16[idx] = as_u32(h);
}

// ---------------- conversion: W_ih -> f16 padded, W_hh -> packed half2 [512][64], bias sum ----------------
__global__ __launch_bounds__(256) void conv_small(const float* __restrict__ Wih, const float* __restrict__ Whh,
      const float* __restrict__ bih, const float* __restrict__ bhh,
      unsigned int* __restrict__ W16, unsigned int* __restrict__ Whh2, float* __restrict__ bias){
  int idx = blockIdx.x*256 + threadIdx.x;
  if (idx < G4*160){
    int r = idx/160, kk2 = idx - r*160, kk = kk2*2;
    const float* wr = Wih + (size_t)r*Ii;
    float v0 = (kk   < Ii) ? wr[kk]   : 0.f;
    float v1 = (kk+1 < Ii) ? wr[kk+1] : 0.f;
    h2v h; h[0]=(_Float16)v0; h[1]=(_Float16)v1;
    W16[idx] = as_u32(h);
  } else if (idx < G4*160 + G4*64){
    int t = idx - G4*160; int j = t>>6, kk = t&63;
    float v0 = Whh[j*Hh + kk*2], v1 = Whh[j*Hh + kk*2 + 1];
    h2v h; h[0]=(_Float16)v0; h[1]=(_Float16)v1;
    Whh2[t] = as_u32(h);
  } else if (idx < G4*160 + G4*64 + G4){
    int d = idx - (G4*160 + G4*64);
    bias[d] = bih[d] + bhh[d];
  }
}

// ---------------- phase 1: xg[131072,512] = A16 @ W16^T + bias, f16 MFMA ----------------
__global__ __launch_bounds__(256,2) void gemm16(const _Float16* __restrict__ A, const _Float16* __restrict__ Bm,
       const float* __restrict__ bias, float* __restrict__ C){
  __shared__ _Float16 As[128][32];
  __shared__ _Float16 Bs[128][32];
  int tid = threadIdx.x;
  int w = tid>>6, lane = tid&63;
  int bm = blockIdx.x*128, bn = blockIdx.y*128;
  f32x4 acc[2][8];
  #pragma unroll
  for (int i=0;i<2;i++)
    #pragma unroll
    for (int j=0;j<8;j++) acc[i][j] = (f32x4){0.f,0.f,0.f,0.f};

  int srow = tid>>1, scol = (tid&1)*16;
  const uint4* ga = (const uint4*)(A  + (size_t)(bm+srow)*KP + scol);
  const uint4* gb = (const uint4*)(Bm + (size_t)(bn+srow)*KP + scol);

  int q = lane>>4, mr = lane&15;
  int m0 = w*32;

  for (int kt=0; kt<KP/32; ++kt){
    __syncthreads();
    uint4 va0 = ga[0], va1 = ga[1];
    uint4 vb0 = gb[0], vb1 = gb[1];
    *(uint4*)&As[srow][scol]   = va0; *(uint4*)&As[srow][scol+8] = va1;
    *(uint4*)&Bs[srow][scol]   = vb0; *(uint4*)&Bs[srow][scol+8] = vb1;
    ga += 4; gb += 4;  // advance 32 halves within the row
    __syncthreads();
    half8 af0 = *(const half8*)&As[m0 + mr][q*8];
    half8 af1 = *(const half8*)&As[m0 + 16 + mr][q*8];
    #pragma unroll
    for (int j=0;j<8;j++){
      half8 bf = *(const half8*)&Bs[j*16 + mr][q*8];
      acc[0][j] = __builtin_amdgcn_mfma_f32_16x16x32_f16(af0, bf, acc[0][j], 0,0,0);
      acc[1][j] = __builtin_amdgcn_mfma_f32_16x16x32_f16(af1, bf, acc[1][j], 0,0,0);
    }
  }
  // epilogue: C/D layout col=lane&15, row=(lane>>4)*4+reg
  #pragma unroll
  for (int j=0;j<8;j++){
    int gc = bn + j*16 + mr;
    float bv = bias[gc];
    #pragma unroll
    for (int i=0;i<2;i++){
      int gr0 = bm + w*32 + i*16 + q*4;
      #pragma unroll
      for (int reg=0; reg<4; ++reg)
        C[(size_t)(gr0+reg)*G4 + gc] = acc[i][j][reg] + bv;
    }
  }
}

// ---------------- phase 2: recurrence, one block per batch row ----------------
// Thread t owns gate rows t and t+256. W_hh in VGPRs (f16 half2). h broadcast via LDS.
__global__ __launch_bounds__(256,1) void lstm_rec(const float* __restrict__ xg, const unsigned int* __restrict__ Whh2,
     const float* __restrict__ fcw, const float* __restrict__ fcb, float* __restrict__ out){
  int tid = threadIdx.x;
  int b = blockIdx.x;
  h2v w0[64], w1[64];
  #pragma unroll
  for (int kk=0; kk<64; ++kk){
    w0[kk] = as_h2(Whh2[tid*64 + kk]);
    w1[kk] = as_h2(Whh2[(tid+256)*64 + kk]);
  }
  __shared__ __align__(16) unsigned short hsh[128];
  __shared__ float2 fo_sh[128];
  __shared__ float red[256];
  if (tid < 128) hsh[tid] = 0;
  float creg = 0.f, hreg = 0.f;
  const float* xrow = xg + (size_t)b * (Tt*G4);
  float xc0 = xrow[tid], xc1 = xrow[256+tid];
  __syncthreads();

  for (int t=0; t<Tt; ++t){
    float xn0 = 0.f, xn1 = 0.f;
    if (t < Tt-1){ const float* xr = xrow + (size_t)(t+1)*G4; xn0 = xr[tid]; xn1 = xr[256+tid]; }
    float a0 = xc0, a1 = xc1;
    const uint4* hv = (const uint4*)hsh;
    #pragma unroll
    for (int kq=0; kq<16; ++kq){
      uint4 hq = hv[kq];
      h2v p0 = as_h2(hq.x), p1 = as_h2(hq.y), p2 = as_h2(hq.z), p3 = as_h2(hq.w);
      a0 = FDOT2(p0, w0[kq*4+0], a0); a1 = FDOT2(p0, w1[kq*4+0], a1);
      a0 = FDOT2(p1, w0[kq*4+1], a0); a1 = FDOT2(p1, w1[kq*4+1], a1);
      a0 = FDOT2(p2, w0[kq*4+2], a0); a1 = FDOT2(p2, w1[kq*4+2], a1);
      a0 = FDOT2(p3, w0[kq*4+3], a0); a1 = FDOT2(p3, w1[kq*4+3], a1);
    }
    if (tid >= 128){
      float f = 1.f/(1.f+__expf(-a0));   // gate f_d, d=tid-128
      float o = 1.f/(1.f+__expf(-a1));   // gate o_d
      fo_sh[tid-128] = make_float2(f,o);
    }
    __syncthreads();
    if (tid < 128){
      float ig = 1.f/(1.f+__expf(-a0));                 // gate i_d
      float eg = __expf(2.f*a1); float g = 1.f - 2.f/(eg+1.f);  // tanh, gate g_d
      float2 fo = fo_sh[tid];
      creg = fo.x*creg + ig*g;
      float ec = __expf(2.f*creg); float tc = 1.f - 2.f/(ec+1.f);
      hreg = fo.y*tc;
      union { _Float16 f; unsigned short s; } cv; cv.f = (_Float16)hreg;
      hsh[tid] = cv.s;
    }
    __syncthreads();
    xc0 = xn0; xc1 = xn1;
  }

  // fused FC: out[b] = sum_d h_d * fcw[d] + fcb
  red[tid] = (tid < 128) ? hreg*fcw[tid] : 0.f;
  __syncthreads();
  for (int s=128; s>=1; s>>=1){
    if (tid < s) red[tid] += red[tid+s];
    __syncthreads();
  }
  if (tid == 0) out[b] = red[0] + fcb[0];
}

extern "C" void kernel_launch(void* const* d_in, const int* in_sizes, int n_in,
                              void* d_out, int out_size, void* d_ws, size_t ws_size,
                              hipStream_t stream){
  const float* x   = (const float*)d_in[0];
  const float* Wih = (const float*)d_in[1];
  const float* Whh = (const float*)d_in[2];
  const float* bih = (const float*)d_in[3];
  const float* bhh = (const float*)d_in[4];
  const float* fcw = (const float*)d_in[5];
  const float* fcb = (const float*)d_in[6];
  float* out = (float*)d_out;
  char* ws = (char*)d_ws;

  // ws layout (bytes):
  //   x16  : 0          .. 83,886,080   (131072*320 f16)
  //   W16  : 83,886,080 .. +327,680     (512*320 f16)
  //   Whh2 : 84,213,760 .. +131,072     (512*64 half2)
  //   bias : 84,344,832 .. +2,048       (512 f32)
  //   xg   : 84,346,880 .. +268,435,456 (131072*512 f32)
  unsigned int* x16   = (unsigned int*)(ws);
  unsigned int* W16   = (unsigned int*)(ws + 83886080);
  unsigned int* Whh2w = (unsigned int*)(ws + 84213760);
  float*        bias  = (float*)      (ws + 84344832);
  float*        xg    = (float*)      (ws + 84346880);

  hipLaunchKernelGGL(conv_x,     dim3(81920),  dim3(256), 0, stream, x, x16);
  hipLaunchKernelGGL(conv_small, dim3(450),    dim3(256), 0, stream, Wih, Whh, bih, bhh, W16, Whh2w, bias);
  hipLaunchKernelGGL(gemm16,     dim3(1024,4), dim3(256), 0, stream,
                     (const _Float16*)x16, (const _Float16*)W16, bias, xg);
  hipLaunchKernelGGL(lstm_rec,   dim3(256),    dim3(256), 0, stream, xg, Whh2w, fcw, fcb, out);
}

// Round 2
// 661.809 us; speedup vs baseline: 1.0698x; 1.0698x over previous
//
#include <hip/hip_runtime.h>
#include <cstdint>
#include <cstddef>

// Problem constants
#define Bb   256
#define Tt   512
#define Ii   300
#define Hh   128
#define G4   512      // 4*H
#define KP   320      // K padded to multiple of 32 for MFMA
#define Mm   (Bb*Tt)  // 131072 rows of phase-1 GEMM

typedef _Float16 h2v   __attribute__((ext_vector_type(2)));
typedef _Float16 half8 __attribute__((ext_vector_type(8)));
typedef float    f32x4 __attribute__((ext_vector_type(4)));

static __device__ __forceinline__ h2v as_h2(unsigned int u){ union{unsigned int u; h2v h;} c; c.u=u; return c.h; }
static __device__ __forceinline__ unsigned int as_u32(h2v h){ union{unsigned int u; h2v h;} c; c.h=h; return c.u; }

#if __has_builtin(__builtin_amdgcn_fdot2)
#define FDOT2(a,b,c) __builtin_amdgcn_fdot2((a),(b),(c),false)
#else
static __device__ __forceinline__ float FDOT2(h2v a, h2v b, float c){
  return c + (float)a[0]*(float)b[0] + (float)a[1]*(float)b[1];
}
#endif

// ---------------- conversion: x fp32 [131072,300] -> f16 padded [131072,320] ----------------
__global__ __launch_bounds__(256) void conv_x(const float* __restrict__ x, unsigned int* __restrict__ x16){
  int idx = blockIdx.x*256 + threadIdx.x;      // half2 index; total 131072*160, grid exact
  int r   = idx / 160;
  int kk2 = idx - r*160;
  int kk  = kk2*2;
  const float* xr = x + (size_t)r*Ii;
  float v0 = (kk   < Ii) ? xr[kk]   : 0.f;
  float v1 = (kk+1 < Ii) ? xr[kk+1] : 0.f;
  h2v h; h[0] = (_Float16)v0; h[1] = (_Float16)v1;
  x16[idx] = as_u32(h);
}

// ---------------- conversion: W_ih -> f16 padded, W_hh -> packed half2 [512][64], bias sum ----------------
__global__ __launch_bounds__(256) void conv_small(const float* __restrict__ Wih, const float* __restrict__ Whh,
      const float* __restrict__ bih, const float* __restrict__ bhh,
      unsigned int* __restrict__ W16, unsigned int* __restrict__ Whh2, float* __restrict__ bias){
  int idx = blockIdx.x*256 + threadIdx.x;
  if (idx < G4*160){
    int r = idx/160, kk2 = idx - r*160, kk = kk2*2;
    const float* wr = Wih + (size_t)r*Ii;
    float v0 = (kk   < Ii) ? wr[kk]   : 0.f;
    float v1 = (kk+1 < Ii) ? wr[kk+1] : 0.f;
    h2v h; h[0]=(_Float16)v0; h[1]=(_Float16)v1;
    W16[idx] = as_u32(h);
  } else if (idx < G4*160 + G4*64){
    int t = idx - G4*160; int j = t>>6, kk = t&63;
    float v0 = Whh[j*Hh + kk*2], v1 = Whh[j*Hh + kk*2 + 1];
    h2v h; h[0]=(_Float16)v0; h[1]=(_Float16)v1;
    Whh2[t] = as_u32(h);
  } else if (idx < G4*160 + G4*64 + G4){
    int d = idx - (G4*160 + G4*64);
    bias[d] = bih[d] + bhh[d];
  }
}

// ---------------- phase 1: xg[131072,512] = A16 @ W16^T + bias, f16 MFMA ----------------
__global__ __launch_bounds__(256,2) void gemm16(const _Float16* __restrict__ A, const _Float16* __restrict__ Bm,
       const float* __restrict__ bias, float* __restrict__ C){
  __shared__ _Float16 As[128][32];
  __shared__ _Float16 Bs[128][32];
  int tid = threadIdx.x;
  int w = tid>>6, lane = tid&63;
  int bm = blockIdx.x*128, bn = blockIdx.y*128;
  f32x4 acc[2][8];
  #pragma unroll
  for (int i=0;i<2;i++)
    #pragma unroll
    for (int j=0;j<8;j++) acc[i][j] = (f32x4){0.f,0.f,0.f,0.f};

  int srow = tid>>1, scol = (tid&1)*16;
  const uint4* ga = (const uint4*)(A  + (size_t)(bm+srow)*KP + scol);
  const uint4* gb = (const uint4*)(Bm + (size_t)(bn+srow)*KP + scol);

  int q = lane>>4, mr = lane&15;
  int m0 = w*32;

  for (int kt=0; kt<KP/32; ++kt){
    __syncthreads();
    uint4 va0 = ga[0], va1 = ga[1];
    uint4 vb0 = gb[0], vb1 = gb[1];
    *(uint4*)&As[srow][scol]   = va0; *(uint4*)&As[srow][scol+8] = va1;
    *(uint4*)&Bs[srow][scol]   = vb0; *(uint4*)&Bs[srow][scol+8] = vb1;
    ga += 4; gb += 4;  // advance 32 halves within the row
    __syncthreads();
    half8 af0 = *(const half8*)&As[m0 + mr][q*8];
    half8 af1 = *(const half8*)&As[m0 + 16 + mr][q*8];
    #pragma unroll
    for (int j=0;j<8;j++){
      half8 bf = *(const half8*)&Bs[j*16 + mr][q*8];
      acc[0][j] = __builtin_amdgcn_mfma_f32_16x16x32_f16(af0, bf, acc[0][j], 0,0,0);
      acc[1][j] = __builtin_amdgcn_mfma_f32_16x16x32_f16(af1, bf, acc[1][j], 0,0,0);
    }
  }
  // epilogue: C/D layout col=lane&15, row=(lane>>4)*4+reg
  #pragma unroll
  for (int j=0;j<8;j++){
    int gc = bn + j*16 + mr;
    float bv = bias[gc];
    #pragma unroll
    for (int i=0;i<2;i++){
      int gr0 = bm + w*32 + i*16 + q*4;
      #pragma unroll
      for (int reg=0; reg<4; ++reg)
        C[(size_t)(gr0+reg)*G4 + gc] = acc[i][j][reg] + bv;
    }
  }
}

// ---------------- phase 2: recurrence, one block per batch row ----------------
// 512 threads; thread t owns gate row t (64 half2 weight VGPRs -> no AGPR eviction).
// c/h update computed redundantly by all 4 gate replicas of each d (float4 gate read).
__global__ __launch_bounds__(512,2) void lstm_rec(const float* __restrict__ xg, const unsigned int* __restrict__ Whh2,
     const float* __restrict__ fcw, const float* __restrict__ fcb, float* __restrict__ out){
  int tid = threadIdx.x;           // 0..511
  int b = blockIdx.x;
  int d = tid & 127, g = tid >> 7; // g uniform per wave (wave=64, 128|gate stride)
  h2v w[64];
  #pragma unroll
  for (int kk=0; kk<64; ++kk) w[kk] = as_h2(Whh2[tid*64 + kk]);

  __shared__ __align__(16) unsigned short hsh[128];
  __shared__ __align__(16) float gsh[512];   // [d*4+g]
  __shared__ float red[128];
  if (tid < 128) hsh[tid] = 0;
  float creg = 0.f, hreg = 0.f;
  const float* xrow = xg + (size_t)b * (Tt*G4);
  float xc = xrow[tid];
  __syncthreads();

  for (int t=0; t<Tt; ++t){
    float xn = 0.f;
    if (t < Tt-1) xn = xrow[(size_t)(t+1)*G4 + tid];
    float a0 = xc, a1 = 0.f;
    const uint4* hv = (const uint4*)hsh;
    #pragma unroll
    for (int kq=0; kq<8; ++kq){
      uint4 hq0 = hv[kq*2], hq1 = hv[kq*2+1];
      a0 = FDOT2(as_h2(hq0.x), w[kq*8+0], a0); a1 = FDOT2(as_h2(hq0.y), w[kq*8+1], a1);
      a0 = FDOT2(as_h2(hq0.z), w[kq*8+2], a0); a1 = FDOT2(as_h2(hq0.w), w[kq*8+3], a1);
      a0 = FDOT2(as_h2(hq1.x), w[kq*8+4], a0); a1 = FDOT2(as_h2(hq1.y), w[kq*8+5], a1);
      a0 = FDOT2(as_h2(hq1.z), w[kq*8+6], a0); a1 = FDOT2(as_h2(hq1.w), w[kq*8+7], a1);
    }
    float a = a0 + a1;
    float act;
    if (g == 2){ float e = __expf(2.f*a); act = 1.f - 2.f/(e+1.f); }      // tanh
    else       { act = 1.f/(1.f+__expf(-a)); }                            // sigmoid
    gsh[d*4+g] = act;
    __syncthreads();
    float4 gv = *(const float4*)&gsh[d*4];   // i,f,g,o for dim d
    creg = gv.y*creg + gv.x*gv.z;
    float ec = __expf(2.f*creg); float tc = 1.f - 2.f/(ec+1.f);
    hreg = gv.w*tc;
    if (g == 0){
      union{ _Float16 f; unsigned short s; } cv; cv.f = (_Float16)hreg;
      hsh[d] = cv.s;
    }
    __syncthreads();
    xc = xn;
  }

  // fused FC: out[b] = sum_d h_d * fcw[d] + fcb
  if (tid < 128) red[tid] = hreg * fcw[tid];
  __syncthreads();
  #pragma unroll
  for (int s=64; s>=1; s>>=1){
    if (tid < s) red[tid] += red[tid+s];
    __syncthreads();
  }
  if (tid == 0) out[b] = red[0] + fcb[0];
}

extern "C" void kernel_launch(void* const* d_in, const int* in_sizes, int n_in,
                              void* d_out, int out_size, void* d_ws, size_t ws_size,
                              hipStream_t stream){
  const float* x   = (const float*)d_in[0];
  const float* Wih = (const float*)d_in[1];
  const float* Whh = (const float*)d_in[2];
  const float* bih = (const float*)d_in[3];
  const float* bhh = (const float*)d_in[4];
  const float* fcw = (const float*)d_in[5];
  const float* fcb = (const float*)d_in[6];
  float* out = (float*)d_out;
  char* ws = (char*)d_ws;

  // ws layout (bytes):
  //   x16  : 0          .. 83,886,080   (131072*320 f16)
  //   W16  : 83,886,080 .. +327,680     (512*320 f16)
  //   Whh2 : 84,213,760 .. +131,072     (512*64 half2)
  //   bias : 84,344,832 .. +2,048       (512 f32)
  //   xg   : 84,346,880 .. +268,435,456 (131072*512 f32)
  unsigned int* x16   = (unsigned int*)(ws);
  unsigned int* W16   = (unsigned int*)(ws + 83886080);
  unsigned int* Whh2w = (unsigned int*)(ws + 84213760);
  float*        bias  = (float*)      (ws + 84344832);
  float*        xg    = (float*)      (ws + 84346880);

  hipLaunchKernelGGL(conv_x,     dim3(81920),  dim3(256), 0, stream, x, x16);
  hipLaunchKernelGGL(conv_small, dim3(450),    dim3(256), 0, stream, Wih, Whh, bih, bhh, W16, Whh2w, bias);
  hipLaunchKernelGGL(gemm16,     dim3(1024,4), dim3(256), 0, stream,
                     (const _Float16*)x16, (const _Float16*)W16, bias, xg);
  hipLaunchKernelGGL(lstm_rec,   dim3(256),    dim3(512), 0, stream, xg, Whh2w, fcw, fcb, out);
}